// Round 1
// baseline (119.376 us; speedup 1.0000x reference)
//
#include <hip/hip_runtime.h>

#define EOS_IDX 2

// ---------------------------------------------------------------------------
// Kernel 1: per-row last EOS position.
// One block per batch row; block max-reduce over positions where id == EOS.
// ---------------------------------------------------------------------------
__global__ void eos_kernel(const int* __restrict__ ids, int* __restrict__ last_eos, int S) {
    const int b = blockIdx.x;
    const int* row = ids + (size_t)b * S;
    int m = 0;
    for (int j = threadIdx.x; j < S; j += blockDim.x) {
        if (row[j] == EOS_IDX) m = max(m, j);
    }
    __shared__ int sm[256];
    sm[threadIdx.x] = m;
    __syncthreads();
    for (int s = blockDim.x >> 1; s > 0; s >>= 1) {
        if (threadIdx.x < (unsigned)s) sm[threadIdx.x] = max(sm[threadIdx.x], sm[threadIdx.x + s]);
        __syncthreads();
    }
    if (threadIdx.x == 0) last_eos[b] = sm[0];
}

// ---------------------------------------------------------------------------
// Kernel 2: masked column-sum with S split across blockIdx.y.
// Thread t owns float4 chunk t of the D-vector (D=1024 -> 256 float4 = 256
// threads, one full coalesced 4KiB row per loop iteration). Partial sums are
// atomically accumulated into the fp32 accumulator in d_ws.
// ---------------------------------------------------------------------------
__global__ void pool_kernel(const float* __restrict__ feat,
                            const int* __restrict__ last_eos,
                            float* __restrict__ acc,
                            int S, int D, int jchunk) {
    const int b  = blockIdx.x;
    const int le = last_eos[b];

    const int j0 = blockIdx.y * jchunk;
    const int lo = max(j0, 1);
    const int hi = min(j0 + jchunk, le);

    const int d4n = D >> 2;
    const float4* base = (const float4*)(feat + (size_t)b * S * D);

    for (int d4 = threadIdx.x; d4 < d4n; d4 += blockDim.x) {
        float4 sum = make_float4(0.f, 0.f, 0.f, 0.f);
        for (int j = lo; j < hi; ++j) {
            float4 v = base[(size_t)j * d4n + d4];
            sum.x += v.x; sum.y += v.y; sum.z += v.z; sum.w += v.w;
        }
        if (hi > lo) {
            float* out = acc + (size_t)b * D + 4 * d4;
            atomicAdd(out + 0, sum.x);
            atomicAdd(out + 1, sum.y);
            atomicAdd(out + 2, sum.z);
            atomicAdd(out + 3, sum.w);
        }
    }
}

// ---------------------------------------------------------------------------
// Kernel 3: divide by count = last_eos - 1.
// ---------------------------------------------------------------------------
__global__ void div_kernel(const float* __restrict__ acc,
                           const int* __restrict__ last_eos,
                           float* __restrict__ out, int D, int n) {
    const int i = blockIdx.x * blockDim.x + threadIdx.x;
    if (i < n) {
        const int b = i / D;
        const float cnt = (float)(last_eos[b] - 1);
        out[i] = acc[i] / cnt;
    }
}

extern "C" void kernel_launch(void* const* d_in, const int* in_sizes, int n_in,
                              void* d_out, int out_size, void* d_ws, size_t ws_size,
                              hipStream_t stream) {
    const float* feat = (const float*)d_in[0];
    const int*   ids  = (const int*)d_in[1];

    const int BS = in_sizes[1];            // B*S
    const int D  = in_sizes[0] / BS;       // 1024
    const int B  = out_size / D;           // 64
    const int S  = BS / B;                 // 2048

    float* acc      = (float*)d_ws;                                    // B*D floats
    int*   last_eos = (int*)((char*)d_ws + (size_t)B * D * sizeof(float));

    hipMemsetAsync(acc, 0, (size_t)B * D * sizeof(float), stream);

    eos_kernel<<<B, 256, 0, stream>>>(ids, last_eos, S);

    constexpr int NSPLIT = 16;
    const int jchunk = (S + NSPLIT - 1) / NSPLIT;
    dim3 grid(B, NSPLIT);
    pool_kernel<<<grid, 256, 0, stream>>>(feat, last_eos, acc, S, D, jchunk);

    const int n = B * D;
    div_kernel<<<(n + 255) / 256, 256, 0, stream>>>(acc, last_eos, (float*)d_out, D, n);
}

// Round 2
// 98.020 us; speedup vs baseline: 1.2179x; 1.2179x over previous
//
#include <hip/hip_runtime.h>

#define EOS_IDX 2
#define NSPLIT 32

typedef float v4f __attribute__((ext_vector_type(4)));

// Block-wide last-EOS scan of one ids row. All threads must call; returns the
// block-uniform max position where row[j] == EOS_IDX (0 if none).
__device__ __forceinline__ int row_last_eos(const int* __restrict__ row, int S) {
    int m = 0;
    for (int j = threadIdx.x; j < S; j += blockDim.x) {
        if (row[j] == EOS_IDX) m = max(m, j);
    }
    // wave(64) butterfly reduce
    #pragma unroll
    for (int off = 32; off > 0; off >>= 1) m = max(m, __shfl_xor(m, off, 64));
    __shared__ int sm[8];
    const int wid = threadIdx.x >> 6;
    const int nw  = blockDim.x >> 6;
    if ((threadIdx.x & 63) == 0) sm[wid] = m;
    __syncthreads();
    int r = sm[0];
    for (int w = 1; w < nw; ++w) r = max(r, sm[w]);
    return r;
}

// ---------------------------------------------------------------------------
// Pool: grid (B, NSPLIT), 256 threads. Each block computes last_eos for its
// row (ids are L2-resident), then sums its S-chunk of masked rows into a
// deterministic partial buffer. Feature is streamed once with non-temporal
// loads; thread t owns float4 column t -> each j-iteration is a fully
// coalesced 4 KiB row read per block.
// ---------------------------------------------------------------------------
__global__ __launch_bounds__(256) void pool_kernel(const float* __restrict__ feat,
                                                   const int* __restrict__ ids,
                                                   float* __restrict__ partial,
                                                   int S, int D, int jchunk) {
    const int b  = blockIdx.x;
    const int le = row_last_eos(ids + (size_t)b * S, S);

    const int j0 = blockIdx.y * jchunk;
    const int lo = max(j0, 1);
    const int hi = min(j0 + jchunk, le);

    const int d4n = D >> 2;
    const v4f* base = (const v4f*)(feat + (size_t)b * S * D);
    v4f* pout = (v4f*)(partial + ((size_t)b * NSPLIT + blockIdx.y) * D);

    for (int d4 = threadIdx.x; d4 < d4n; d4 += blockDim.x) {
        v4f s0 = {0.f, 0.f, 0.f, 0.f};
        v4f s1 = s0, s2 = s0, s3 = s0;
        int j = lo;
        for (; j + 4 <= hi; j += 4) {
            v4f a0 = __builtin_nontemporal_load(base + (size_t)(j + 0) * d4n + d4);
            v4f a1 = __builtin_nontemporal_load(base + (size_t)(j + 1) * d4n + d4);
            v4f a2 = __builtin_nontemporal_load(base + (size_t)(j + 2) * d4n + d4);
            v4f a3 = __builtin_nontemporal_load(base + (size_t)(j + 3) * d4n + d4);
            s0 += a0; s1 += a1; s2 += a2; s3 += a3;
        }
        for (; j < hi; ++j)
            s0 += __builtin_nontemporal_load(base + (size_t)j * d4n + d4);
        // always write (ws is poisoned, not zeroed)
        pout[d4] = (s0 + s1) + (s2 + s3);
    }
}

// ---------------------------------------------------------------------------
// Reduce: grid (B, ceil(D/256)). Sums the NSPLIT partials per (b,d) and
// divides by count = last_eos - 1 (re-derived from the L2-hot ids row).
// ---------------------------------------------------------------------------
__global__ __launch_bounds__(256) void reduce_kernel(const float* __restrict__ partial,
                                                     const int* __restrict__ ids,
                                                     float* __restrict__ out,
                                                     int S, int D) {
    const int b  = blockIdx.x;
    const int le = row_last_eos(ids + (size_t)b * S, S);
    const float inv = 1.0f / (float)(le - 1);

    const int d = blockIdx.y * blockDim.x + threadIdx.x;
    if (d < D) {
        const float* p = partial + (size_t)b * NSPLIT * D + d;
        float s = 0.f;
        #pragma unroll
        for (int t = 0; t < NSPLIT; ++t) s += p[(size_t)t * D];
        out[(size_t)b * D + d] = s * inv;
    }
}

extern "C" void kernel_launch(void* const* d_in, const int* in_sizes, int n_in,
                              void* d_out, int out_size, void* d_ws, size_t ws_size,
                              hipStream_t stream) {
    const float* feat = (const float*)d_in[0];
    const int*   ids  = (const int*)d_in[1];

    const int BS = in_sizes[1];            // B*S
    const int D  = in_sizes[0] / BS;       // 1024
    const int B  = out_size / D;           // 64
    const int S  = BS / B;                 // 2048

    float* partial = (float*)d_ws;         // B * NSPLIT * D floats

    const int jchunk = (S + NSPLIT - 1) / NSPLIT;
    dim3 pgrid(B, NSPLIT);
    pool_kernel<<<pgrid, 256, 0, stream>>>(feat, ids, partial, S, D, jchunk);

    dim3 rgrid(B, (D + 255) / 256);
    reduce_kernel<<<rgrid, 256, 0, stream>>>(partial, ids, (float*)d_out, S, D);
}

// Round 3
// 89.596 us; speedup vs baseline: 1.3324x; 1.0940x over previous
//
#include <hip/hip_runtime.h>

#define EOS_IDX 2
#define NSPLIT 16

typedef float v4f __attribute__((ext_vector_type(4)));

// Block-wide last-EOS scan of one ids row. All threads must call; returns the
// block-uniform max position where row[j] == EOS_IDX (0 if none).
__device__ __forceinline__ int row_last_eos(const int* __restrict__ row, int S) {
    int m = 0;
    for (int j = threadIdx.x; j < S; j += blockDim.x) {
        if (row[j] == EOS_IDX) m = max(m, j);
    }
    #pragma unroll
    for (int off = 32; off > 0; off >>= 1) m = max(m, __shfl_xor(m, off, 64));
    __shared__ int sm[8];
    const int wid = threadIdx.x >> 6;
    const int nw  = blockDim.x >> 6;
    if ((threadIdx.x & 63) == 0) sm[wid] = m;
    __syncthreads();
    int r = sm[0];
    for (int w = 1; w < nw; ++w) r = max(r, sm[w]);
    return r;
}

// ---------------------------------------------------------------------------
// Pool: grid (B, NSPLIT), 256 threads. Each block derives last_eos for its row
// (ids row is 8 KB, L2-hot), streams its S-chunk with 8-deep independent
// float4 accumulators (8x16B outstanding loads/thread), and writes its
// PRE-SCALED (x 1/(le-1)) partial sum. Partials are written unconditionally
// (ws is poisoned, not zeroed).
// ---------------------------------------------------------------------------
__global__ __launch_bounds__(256) void pool_kernel(const float* __restrict__ feat,
                                                   const int* __restrict__ ids,
                                                   float* __restrict__ partial,
                                                   int S, int D, int jchunk) {
    const int b  = blockIdx.x;
    const int le = row_last_eos(ids + (size_t)b * S, S);
    const float inv = 1.0f / (float)(le - 1);

    const int j0 = blockIdx.y * jchunk;
    const int lo = max(j0, 1);
    const int hi = min(j0 + jchunk, le);

    const int d4n = D >> 2;
    const v4f* base = (const v4f*)(feat + (size_t)b * S * D);
    v4f* pout = (v4f*)(partial + ((size_t)b * NSPLIT + blockIdx.y) * D);

    for (int d4 = threadIdx.x; d4 < d4n; d4 += blockDim.x) {
        v4f s0 = {0.f, 0.f, 0.f, 0.f};
        v4f s1 = s0, s2 = s0, s3 = s0, s4 = s0, s5 = s0, s6 = s0, s7 = s0;
        int j = lo;
        for (; j + 8 <= hi; j += 8) {
            const v4f* p = base + (size_t)j * d4n + d4;
            v4f a0 = __builtin_nontemporal_load(p + 0 * d4n);
            v4f a1 = __builtin_nontemporal_load(p + 1 * d4n);
            v4f a2 = __builtin_nontemporal_load(p + 2 * d4n);
            v4f a3 = __builtin_nontemporal_load(p + 3 * d4n);
            v4f a4 = __builtin_nontemporal_load(p + 4 * d4n);
            v4f a5 = __builtin_nontemporal_load(p + 5 * d4n);
            v4f a6 = __builtin_nontemporal_load(p + 6 * d4n);
            v4f a7 = __builtin_nontemporal_load(p + 7 * d4n);
            s0 += a0; s1 += a1; s2 += a2; s3 += a3;
            s4 += a4; s5 += a5; s6 += a6; s7 += a7;
        }
        for (; j < hi; ++j)
            s0 += __builtin_nontemporal_load(base + (size_t)j * d4n + d4);
        v4f t = ((s0 + s1) + (s2 + s3)) + ((s4 + s5) + (s6 + s7));
        pout[d4] = t * inv;
    }
}

// ---------------------------------------------------------------------------
// Reduce: one block per row; float4 sum of the NSPLIT pre-scaled partials.
// ---------------------------------------------------------------------------
__global__ __launch_bounds__(256) void reduce_kernel(const float* __restrict__ partial,
                                                     float* __restrict__ out, int D) {
    const int b   = blockIdx.x;
    const int d4n = D >> 2;
    const v4f* p  = (const v4f*)(partial + (size_t)b * NSPLIT * D);
    v4f* o        = (v4f*)(out + (size_t)b * D);
    for (int d4 = threadIdx.x; d4 < d4n; d4 += blockDim.x) {
        v4f s = {0.f, 0.f, 0.f, 0.f};
        #pragma unroll
        for (int t = 0; t < NSPLIT; ++t) s += p[(size_t)t * d4n + d4];
        o[d4] = s;
    }
}

extern "C" void kernel_launch(void* const* d_in, const int* in_sizes, int n_in,
                              void* d_out, int out_size, void* d_ws, size_t ws_size,
                              hipStream_t stream) {
    const float* feat = (const float*)d_in[0];
    const int*   ids  = (const int*)d_in[1];

    const int BS = in_sizes[1];            // B*S
    const int D  = in_sizes[0] / BS;       // 1024
    const int B  = out_size / D;           // 64
    const int S  = BS / B;                 // 2048

    float* partial = (float*)d_ws;         // B * NSPLIT * D floats

    const int jchunk = (S + NSPLIT - 1) / NSPLIT;
    dim3 pgrid(B, NSPLIT);
    pool_kernel<<<pgrid, 256, 0, stream>>>(feat, ids, partial, S, D, jchunk);

    reduce_kernel<<<B, 256, 0, stream>>>(partial, (float*)d_out, D);
}